// Round 1
// baseline (473.954 us; speedup 1.0000x reference)
//
#include <hip/hip_runtime.h>
#include <hip/hip_bf16.h>
#include <math.h>

// Problem constants
constexpr int Bc = 32, Nn = 500, Mm = 500, Dd = 256;
constexpr float INV_SQRT_D = 1.0f / 16.0f;
constexpr float LOGIT_CLIP = 10.0f;

// GEMM tiling
constexpr int TS = 64;          // output tile (rows x cols)
constexpr int KC = 32;          // k-chunk
constexpr int LDSW = TS + 4;    // padded LDS row width (keeps float4 alignment)

__device__ __forceinline__ void fma16(float (&acc)[4][4], const float4& a, const float4& b) {
    const float av[4] = {a.x, a.y, a.z, a.w};
    const float bv[4] = {b.x, b.y, b.z, b.w};
#pragma unroll
    for (int i = 0; i < 4; ++i)
#pragma unroll
        for (int j = 0; j < 4; ++j)
            acc[i][j] = fmaf(av[i], bv[j], acc[i][j]);
}

// ---------------------------------------------------------------------------
// K1: ek = exp(jobs @ Wk^T), ekv = ek * (jobs @ Wv^T)
// rows = B*M = 16000 (exact 250 tiles), cols = 256 (exact 4 tiles)
// ---------------------------------------------------------------------------
__global__ __launch_bounds__(256) void k1_kv(const float* __restrict__ jobs,
                                             const float* __restrict__ Wk,
                                             const float* __restrict__ Wv,
                                             float* __restrict__ ek,
                                             float* __restrict__ ekv) {
    __shared__ float As[KC][LDSW];
    __shared__ float Bk[KC][LDSW];
    __shared__ float Bv[KC][LDSW];
    const int tid = threadIdx.x;
    const int tx = tid & 15, ty = tid >> 4;
    const int C0 = blockIdx.x * TS, R0 = blockIdx.y * TS;

    float ak[4][4] = {}, av[4][4] = {};

    for (int kc = 0; kc < Dd; kc += KC) {
#pragma unroll
        for (int it = 0; it < 2; ++it) {
            const int idx = tid + it * 256;
            const int r = idx >> 3, kp = (idx & 7) << 2;
            float4 a = *(const float4*)&jobs[(size_t)(R0 + r) * Dd + kc + kp];
            As[kp + 0][r] = a.x; As[kp + 1][r] = a.y; As[kp + 2][r] = a.z; As[kp + 3][r] = a.w;
            float4 wk4 = *(const float4*)&Wk[(size_t)(C0 + r) * Dd + kc + kp];
            Bk[kp + 0][r] = wk4.x; Bk[kp + 1][r] = wk4.y; Bk[kp + 2][r] = wk4.z; Bk[kp + 3][r] = wk4.w;
            float4 wv4 = *(const float4*)&Wv[(size_t)(C0 + r) * Dd + kc + kp];
            Bv[kp + 0][r] = wv4.x; Bv[kp + 1][r] = wv4.y; Bv[kp + 2][r] = wv4.z; Bv[kp + 3][r] = wv4.w;
        }
        __syncthreads();
#pragma unroll
        for (int kk = 0; kk < KC; ++kk) {
            float4 a  = *(const float4*)&As[kk][ty << 2];
            float4 b1 = *(const float4*)&Bk[kk][tx << 2];
            float4 b2 = *(const float4*)&Bv[kk][tx << 2];
            fma16(ak, a, b1);
            fma16(av, a, b2);
        }
        __syncthreads();
    }

#pragma unroll
    for (int i = 0; i < 4; ++i) {
        const size_t o = (size_t)(R0 + (ty << 2) + i) * Dd + C0 + (tx << 2);
        float4 e4, ev4;
        e4.x = expf(ak[i][0]); e4.y = expf(ak[i][1]); e4.z = expf(ak[i][2]); e4.w = expf(ak[i][3]);
        ev4.x = e4.x * av[i][0]; ev4.y = e4.y * av[i][1]; ev4.z = e4.z * av[i][2]; ev4.w = e4.w * av[i][3];
        *(float4*)&ek[o] = e4;
        *(float4*)&ekv[o] = ev4;
    }
}

// ---------------------------------------------------------------------------
// K2: sq = sigmoid(q0 @ Wq0^T + q1 @ Wq1^T)
// ---------------------------------------------------------------------------
__global__ __launch_bounds__(256) void k2_q(const float* __restrict__ q0,
                                            const float* __restrict__ q1,
                                            const float* __restrict__ Wq0,
                                            const float* __restrict__ Wq1,
                                            float* __restrict__ sq) {
    __shared__ float A0[KC][LDSW];
    __shared__ float A1[KC][LDSW];
    __shared__ float B0[KC][LDSW];
    __shared__ float B1[KC][LDSW];
    const int tid = threadIdx.x;
    const int tx = tid & 15, ty = tid >> 4;
    const int C0 = blockIdx.x * TS, R0 = blockIdx.y * TS;

    float acc[4][4] = {};

    for (int kc = 0; kc < Dd; kc += KC) {
#pragma unroll
        for (int it = 0; it < 2; ++it) {
            const int idx = tid + it * 256;
            const int r = idx >> 3, kp = (idx & 7) << 2;
            float4 a0 = *(const float4*)&q0[(size_t)(R0 + r) * Dd + kc + kp];
            A0[kp + 0][r] = a0.x; A0[kp + 1][r] = a0.y; A0[kp + 2][r] = a0.z; A0[kp + 3][r] = a0.w;
            float4 a1 = *(const float4*)&q1[(size_t)(R0 + r) * Dd + kc + kp];
            A1[kp + 0][r] = a1.x; A1[kp + 1][r] = a1.y; A1[kp + 2][r] = a1.z; A1[kp + 3][r] = a1.w;
            float4 w0 = *(const float4*)&Wq0[(size_t)(C0 + r) * Dd + kc + kp];
            B0[kp + 0][r] = w0.x; B0[kp + 1][r] = w0.y; B0[kp + 2][r] = w0.z; B0[kp + 3][r] = w0.w;
            float4 w1 = *(const float4*)&Wq1[(size_t)(C0 + r) * Dd + kc + kp];
            B1[kp + 0][r] = w1.x; B1[kp + 1][r] = w1.y; B1[kp + 2][r] = w1.z; B1[kp + 3][r] = w1.w;
        }
        __syncthreads();
#pragma unroll
        for (int kk = 0; kk < KC; ++kk) {
            float4 a0 = *(const float4*)&A0[kk][ty << 2];
            float4 b0 = *(const float4*)&B0[kk][tx << 2];
            fma16(acc, a0, b0);
            float4 a1 = *(const float4*)&A1[kk][ty << 2];
            float4 b1 = *(const float4*)&B1[kk][tx << 2];
            fma16(acc, a1, b1);
        }
        __syncthreads();
    }

#pragma unroll
    for (int i = 0; i < 4; ++i) {
        const size_t o = (size_t)(R0 + (ty << 2) + i) * Dd + C0 + (tx << 2);
        float4 s4;
        s4.x = 1.0f / (1.0f + expf(-acc[i][0]));
        s4.y = 1.0f / (1.0f + expf(-acc[i][1]));
        s4.z = 1.0f / (1.0f + expf(-acc[i][2]));
        s4.w = 1.0f / (1.0f + expf(-acc[i][3]));
        *(float4*)&sq[o] = s4;
    }
}

// ---------------------------------------------------------------------------
// K3: per b: A[n][m] = exp(-a1*ls*cost + mask); num = A@ekv, den = A@ek
//     aafm = sq * nan_to_num(num/den)  (in-place over sq buffer)
// grid: (dTiles=4, nTiles=8, B=32)
// ---------------------------------------------------------------------------
__global__ __launch_bounds__(256) void k3_numden(const float* __restrict__ cost,
                                                 const float* __restrict__ mask,
                                                 const float* __restrict__ ek,
                                                 const float* __restrict__ ekv,
                                                 float* __restrict__ sq_aafm,
                                                 const float* __restrict__ alpha1,
                                                 const float* __restrict__ log_scale) {
    __shared__ float As[KC][LDSW];
    __shared__ float Be[KC][LDSW];
    __shared__ float Bev[KC][LDSW];
    const int tid = threadIdx.x;
    const int tx = tid & 15, ty = tid >> 4;
    const int b = blockIdx.z;
    const int N0 = blockIdx.y * TS, D0 = blockIdx.x * TS;
    const float a1ls = alpha1[0] * log_scale[0];
    const size_t costB = (size_t)b * Nn * Mm;
    const size_t ekB = (size_t)b * Mm * Dd;

    float accn[4][4] = {}, accd[4][4] = {};

    for (int mc = 0; mc < Mm; mc += KC) {
#pragma unroll
        for (int it = 0; it < 2; ++it) {
            const int idx = tid + it * 256;
            // A tile: 64 n x 32 m
            {
                const int r = idx >> 3, kp = (idx & 7) << 2;
                const int ng = N0 + r, mg = mc + kp;
                float4 a = {0.f, 0.f, 0.f, 0.f};
                if (ng < Nn && mg < Mm) {
                    const size_t o = costB + (size_t)ng * Mm + mg;
                    float4 c4 = *(const float4*)&cost[o];
                    float4 m4 = *(const float4*)&mask[o];
                    a.x = expf(fmaf(-a1ls, c4.x, m4.x));
                    a.y = expf(fmaf(-a1ls, c4.y, m4.y));
                    a.z = expf(fmaf(-a1ls, c4.z, m4.z));
                    a.w = expf(fmaf(-a1ls, c4.w, m4.w));
                }
                As[kp + 0][r] = a.x; As[kp + 1][r] = a.y; As[kp + 2][r] = a.z; As[kp + 3][r] = a.w;
            }
            // B tiles: 32 m x 64 d
            {
                const int ml = idx >> 4, dp = (idx & 15) << 2;
                const int mg = mc + ml;
                float4 e4 = {0.f, 0.f, 0.f, 0.f}, ev4 = {0.f, 0.f, 0.f, 0.f};
                if (mg < Mm) {
                    const size_t o = ekB + (size_t)mg * Dd + D0 + dp;
                    e4 = *(const float4*)&ek[o];
                    ev4 = *(const float4*)&ekv[o];
                }
                *(float4*)&Be[ml][dp] = e4;
                *(float4*)&Bev[ml][dp] = ev4;
            }
        }
        __syncthreads();
#pragma unroll
        for (int kk = 0; kk < KC; ++kk) {
            float4 a  = *(const float4*)&As[kk][ty << 2];
            float4 be = *(const float4*)&Be[kk][tx << 2];
            float4 bv = *(const float4*)&Bev[kk][tx << 2];
            fma16(accd, a, be);
            fma16(accn, a, bv);
        }
        __syncthreads();
    }

#pragma unroll
    for (int i = 0; i < 4; ++i) {
        const int ng = N0 + (ty << 2) + i;
        if (ng >= Nn) continue;
        const size_t o = ((size_t)b * Nn + ng) * Dd + D0 + (tx << 2);
        float4 s4 = *(const float4*)&sq_aafm[o];
        float w0 = accd[i][0] != 0.f ? accn[i][0] / accd[i][0] : 0.f;
        float w1 = accd[i][1] != 0.f ? accn[i][1] / accd[i][1] : 0.f;
        float w2 = accd[i][2] != 0.f ? accn[i][2] / accd[i][2] : 0.f;
        float w3 = accd[i][3] != 0.f ? accn[i][3] / accd[i][3] : 0.f;
        float4 r4;
        r4.x = s4.x * w0; r4.y = s4.y * w1; r4.z = s4.z * w2; r4.w = s4.w * w3;
        *(float4*)&sq_aafm[o] = r4;
    }
}

// ---------------------------------------------------------------------------
// K4: logits[b,n,m] = 10*tanh( (aafm@jobs^T)/16 - a2*ls*cost ) + mask
// grid: (mTiles=8, nTiles=8, B=32)
// ---------------------------------------------------------------------------
__global__ __launch_bounds__(256) void k4_score(const float* __restrict__ aafm,
                                                const float* __restrict__ jobs,
                                                const float* __restrict__ cost,
                                                const float* __restrict__ mask,
                                                const float* __restrict__ alpha2,
                                                const float* __restrict__ log_scale,
                                                float* __restrict__ out) {
    __shared__ float As[KC][LDSW];
    __shared__ float Bs[KC][LDSW];
    const int tid = threadIdx.x;
    const int tx = tid & 15, ty = tid >> 4;
    const int b = blockIdx.z;
    const int N0 = blockIdx.y * TS, M0 = blockIdx.x * TS;
    const float a2ls = alpha2[0] * log_scale[0];
    const size_t costB = (size_t)b * Nn * Mm;

    float acc[4][4] = {};

    for (int kc = 0; kc < Dd; kc += KC) {
#pragma unroll
        for (int it = 0; it < 2; ++it) {
            const int idx = tid + it * 256;
            const int r = idx >> 3, kp = (idx & 7) << 2;
            // A: aafm rows (clamp OOB n to stay in-bounds; stores are guarded)
            const int ng = min(N0 + r, Nn - 1);
            float4 a = *(const float4*)&aafm[((size_t)b * Nn + ng) * Dd + kc + kp];
            As[kp + 0][r] = a.x; As[kp + 1][r] = a.y; As[kp + 2][r] = a.z; As[kp + 3][r] = a.w;
            // B: jobs rows as columns (k = d)
            const int mg = min(M0 + r, Mm - 1);
            float4 w = *(const float4*)&jobs[((size_t)b * Mm + mg) * Dd + kc + kp];
            Bs[kp + 0][r] = w.x; Bs[kp + 1][r] = w.y; Bs[kp + 2][r] = w.z; Bs[kp + 3][r] = w.w;
        }
        __syncthreads();
#pragma unroll
        for (int kk = 0; kk < KC; ++kk) {
            float4 a = *(const float4*)&As[kk][ty << 2];
            float4 b4 = *(const float4*)&Bs[kk][tx << 2];
            fma16(acc, a, b4);
        }
        __syncthreads();
    }

    const int mg = M0 + (tx << 2);
    if (mg >= Mm) return;
#pragma unroll
    for (int i = 0; i < 4; ++i) {
        const int ng = N0 + (ty << 2) + i;
        if (ng >= Nn) continue;
        const size_t o = costB + (size_t)ng * Mm + mg;
        float4 c4 = *(const float4*)&cost[o];
        float4 m4 = *(const float4*)&mask[o];
        float4 r4;
        r4.x = LOGIT_CLIP * tanhf(fmaf(-a2ls, c4.x, acc[i][0] * INV_SQRT_D)) + m4.x;
        r4.y = LOGIT_CLIP * tanhf(fmaf(-a2ls, c4.y, acc[i][1] * INV_SQRT_D)) + m4.y;
        r4.z = LOGIT_CLIP * tanhf(fmaf(-a2ls, c4.z, acc[i][2] * INV_SQRT_D)) + m4.z;
        r4.w = LOGIT_CLIP * tanhf(fmaf(-a2ls, c4.w, acc[i][3] * INV_SQRT_D)) + m4.w;
        *(float4*)&out[o] = r4;
    }
}

// ---------------------------------------------------------------------------
// K5: in-place row softmax over M=500. One wave per row, 4 rows per block.
// ---------------------------------------------------------------------------
__global__ __launch_bounds__(256) void k5_softmax(float* __restrict__ out) {
    const int wave = threadIdx.x >> 6;
    const int lane = threadIdx.x & 63;
    const int row = blockIdx.x * 4 + wave;  // grid = 4000 -> rows 0..15999 exactly
    float* p = out + (size_t)row * Mm;

    float4 v1 = *(const float4*)&p[lane << 2];           // f4 index lane (0..63 < 125)
    const bool has2 = lane < 61;                          // 125 f4 total
    float4 v2 = {-1e30f, -1e30f, -1e30f, -1e30f};
    if (has2) v2 = *(const float4*)&p[(64 + lane) << 2];

    float mx = fmaxf(fmaxf(fmaxf(v1.x, v1.y), fmaxf(v1.z, v1.w)),
                     fmaxf(fmaxf(v2.x, v2.y), fmaxf(v2.z, v2.w)));
#pragma unroll
    for (int off = 32; off > 0; off >>= 1) mx = fmaxf(mx, __shfl_xor(mx, off));

    float4 e1, e2;
    e1.x = expf(v1.x - mx); e1.y = expf(v1.y - mx); e1.z = expf(v1.z - mx); e1.w = expf(v1.w - mx);
    e2.x = expf(v2.x - mx); e2.y = expf(v2.y - mx); e2.z = expf(v2.z - mx); e2.w = expf(v2.w - mx);
    float s = e1.x + e1.y + e1.z + e1.w + e2.x + e2.y + e2.z + e2.w;
#pragma unroll
    for (int off = 32; off > 0; off >>= 1) s += __shfl_xor(s, off);

    const float inv = 1.0f / s;
    e1.x *= inv; e1.y *= inv; e1.z *= inv; e1.w *= inv;
    *(float4*)&p[lane << 2] = e1;
    if (has2) {
        e2.x *= inv; e2.y *= inv; e2.z *= inv; e2.w *= inv;
        *(float4*)&p[(64 + lane) << 2] = e2;
    }
}

// ---------------------------------------------------------------------------
extern "C" void kernel_launch(void* const* d_in, const int* in_sizes, int n_in,
                              void* d_out, int out_size, void* d_ws, size_t ws_size,
                              hipStream_t stream) {
    const float* q0        = (const float*)d_in[0];   // (B,N,D)
    const float* jobs      = (const float*)d_in[1];   // (B,M,D)
    const float* q1        = (const float*)d_in[2];   // (B,N,D)
    const float* cost      = (const float*)d_in[3];   // (B,N,M)
    const float* log_scale = (const float*)d_in[4];   // (1,)
    const float* mask      = (const float*)d_in[5];   // (B,N,M)
    const float* Wq0       = (const float*)d_in[6];   // (D,D)
    const float* Wq1       = (const float*)d_in[7];   // (D,D)
    const float* Wk        = (const float*)d_in[8];   // (D,D)
    const float* Wv        = (const float*)d_in[9];   // (D,D)
    const float* alpha1    = (const float*)d_in[10];  // (1,)
    const float* alpha2    = (const float*)d_in[11];  // (1,)
    float* out = (float*)d_out;

    const size_t nBMD = (size_t)Bc * Mm * Dd;  // 4,096,000
    float* ek  = (float*)d_ws;
    float* ekv = ek + nBMD;
    float* sq  = ekv + nBMD;  // overwritten in-place with aafm by K3

    dim3 blk(256);
    k1_kv<<<dim3(4, 250), blk, 0, stream>>>(jobs, Wk, Wv, ek, ekv);
    k2_q<<<dim3(4, 250), blk, 0, stream>>>(q0, q1, Wq0, Wq1, sq);
    k3_numden<<<dim3(4, 8, 32), blk, 0, stream>>>(cost, mask, ek, ekv, sq, alpha1, log_scale);
    k4_score<<<dim3(8, 8, 32), blk, 0, stream>>>(sq, jobs, cost, mask, alpha2, log_scale, out);
    k5_softmax<<<4000, blk, 0, stream>>>(out);
}